// Round 18
// baseline (60.745 us; speedup 1.0000x reference)
//
#include <hip/hip_runtime.h>

#ifndef FLT_MAX
#define FLT_MAX 3.402823466e+38f
#endif

__device__ __forceinline__ float sel3(int i, float a, float b, float c) {
    return i == 0 ? a : (i == 1 ? b : c);
}
__device__ __forceinline__ float sel4(int i, float a, float b, float c, float d) {
    return i == 0 ? a : (i == 1 ? b : (i == 2 ? c : d));
}

// numpy-order exact d2: ((dx*dx + dy*dy) + dz*dz), each op round-to-nearest,
// NO fma — bit-identical to the reference's evaluation order.
__device__ __forceinline__ float d2np(float ax, float ay, float az,
                                      float bx, float by, float bz) {
    const float dx = __fsub_rn(ax, bx);
    const float dy = __fsub_rn(ay, by);
    const float dz = __fsub_rn(az, bz);
    return __fadd_rn(__fadd_rn(__fmul_rn(dx, dx), __fmul_rn(dy, dy)),
                     __fmul_rn(dz, dz));
}

// Pack two f32 -> f16x2 dword (RNE).
__device__ __forceinline__ unsigned pk2(float a, float b) {
    unsigned short ua = __builtin_bit_cast(unsigned short, (_Float16)a);
    unsigned short ub = __builtin_bit_cast(unsigned short, (_Float16)b);
    return (unsigned)ua | ((unsigned)ub << 16);
}
__device__ __forceinline__ float lo16f(unsigned u) {
    return (float)__builtin_bit_cast(_Float16, (unsigned short)(u & 0xFFFFu));
}
__device__ __forceinline__ float hi16f(unsigned u) {
    return (float)__builtin_bit_cast(_Float16, (unsigned short)(u >> 16));
}

// Packed-f16 filter step: 2 pairs in 7 ops (v_pk_*_f16 are true 2-wide).
__device__ __forceinline__ void f16step(unsigned& acc, unsigned rx, unsigned ry,
                                        unsigned rz, unsigned ncx, unsigned ncy,
                                        unsigned ncz) {
    unsigned dx, dy, dz;
    asm("v_pk_add_f16 %0, %4, %7\n\t"
        "v_pk_add_f16 %1, %5, %8\n\t"
        "v_pk_add_f16 %2, %6, %9\n\t"
        "v_pk_mul_f16 %2, %2, %2\n\t"
        "v_pk_fma_f16 %2, %1, %1, %2\n\t"
        "v_pk_fma_f16 %2, %0, %0, %2\n\t"
        "v_pk_min_f16 %3, %3, %2"
        : "=&v"(dx), "=&v"(dy), "=&v"(dz), "+v"(acc)
        : "v"(rx), "v"(ry), "v"(rz), "v"(ncx), "v"(ncy), "v"(ncz));
}

// FOUR edges per wave (16-lane group n owns edge n); lane 16n+t owns rows
// 4t..4t+3 and cols 4t..4t+3 (R9 structure). Phase 1: packed-f16 approx scan
// (3.5 instr/pair). Phase 2: conservative window (rowmin_h <= bm + 2eps,
// eps a rigorous f16-error bound with ~2x margin) provably contains the true
// argmin row; candidates re-scanned EXACTLY in f32 numpy op order, rows
// ascending, first-col ballots -> exact numpy argmin semantics.
// R17 BUG FIXED: LDS planes now at dwords {0,32,64} matching the reads
// (were {0,64,128} — overran the slice and fed garbage y/z planes).
__global__ __launch_bounds__(256, 4) void clustgeo_f16filter(
    const float* __restrict__ data,
    const int*   __restrict__ clusts,
    const int*   __restrict__ eidx,
    float*       __restrict__ out,
    int E)
{
    const int wave = threadIdx.x >> 6;
    const int lane = threadIdx.x & 63;
    const int t    = lane & 15;
    const int gsh  = lane & 48;
    const int e    = blockIdx.x * 16 + wave * 4 + (lane >> 4);
    const int ec   = e < E ? e : (E - 1);

    __shared__ __align__(16) unsigned sx[4][4][112];   // 3 planes x 32 dwords + pad

    const int ca = eidx[ec];
    const int cb = eidx[E + ec];
    const int4 P1 = *reinterpret_cast<const int4*>(clusts + ca * 64 + 4 * t);
    const int4 P2 = *reinterpret_cast<const int4*>(clusts + cb * 64 + 4 * t);
    const float4 q10 = *reinterpret_cast<const float4*>(data + (size_t)P1.x * 4);
    const float4 q11 = *reinterpret_cast<const float4*>(data + (size_t)P1.y * 4);
    const float4 q12 = *reinterpret_cast<const float4*>(data + (size_t)P1.z * 4);
    const float4 q13 = *reinterpret_cast<const float4*>(data + (size_t)P1.w * 4);
    const float4 q20 = *reinterpret_cast<const float4*>(data + (size_t)P2.x * 4);
    const float4 q21 = *reinterpret_cast<const float4*>(data + (size_t)P2.y * 4);
    const float4 q22 = *reinterpret_cast<const float4*>(data + (size_t)P2.z * 4);
    const float4 q23 = *reinterpret_cast<const float4*>(data + (size_t)P2.w * 4);
    const float r0x=q10.y, r0y=q10.z, r0z=q10.w;
    const float r1x=q11.y, r1y=q11.z, r1z=q11.w;
    const float r2x=q12.y, r2y=q12.z, r2z=q12.w;
    const float r3x=q13.y, r3y=q13.z, r3z=q13.w;
    const float c0x=q20.y, c0y=q20.z, c0z=q20.w;
    const float c1x=q21.y, c1y=q21.z, c1z=q21.w;
    const float c2x=q22.y, c2y=q22.z, c2z=q22.w;
    const float c3x=q23.y, c3y=q23.z, c3z=q23.w;

    // Stage NEGATED f16 cols: plane p at dword p*32; colpair (4t,4t+1) at 2t.
    unsigned* slice = &sx[wave][lane >> 4][0];
    slice[2*t]        = pk2(-c0x, -c1x);  slice[2*t + 1]      = pk2(-c2x, -c3x);
    slice[32 + 2*t]   = pk2(-c0y, -c1y);  slice[32 + 2*t + 1] = pk2(-c2y, -c3y);
    slice[64 + 2*t]   = pk2(-c0z, -c1z);  slice[64 + 2*t + 1] = pk2(-c2z, -c3z);
    // No barrier: each group reads only its own slice; same-wave LDS RAW is
    // ordered by compiler-inserted lgkmcnt waits (validated R3-R16).

    const unsigned rr0x = pk2(r0x, r0x), rr0y = pk2(r0y, r0y), rr0z = pk2(r0z, r0z);
    const unsigned rr1x = pk2(r1x, r1x), rr1y = pk2(r1y, r1y), rr1z = pk2(r1z, r1z);
    const unsigned rr2x = pk2(r2x, r2x), rr2y = pk2(r2y, r2y), rr2z = pk2(r2z, r2z);
    const unsigned rr3x = pk2(r3x, r3x), rr3y = pk2(r3y, r3y), rr3z = pk2(r3z, r3z);

    const uint4* SU = reinterpret_cast<const uint4*>(slice);   // plane p: [p*8+g]
    unsigned a0 = 0x7C007C00u, a1 = 0x7C007C00u;   // {+inf,+inf} f16
    unsigned a2 = 0x7C007C00u, a3 = 0x7C007C00u;

    #pragma unroll 2
    for (int g = 0; g < 8; ++g) {       // 8 cols (4 colpairs) per iteration
        const uint4 X = SU[g];
        const uint4 Y = SU[8 + g];
        const uint4 Z = SU[16 + g];
        f16step(a0, rr0x, rr0y, rr0z, X.x, Y.x, Z.x);
        f16step(a0, rr0x, rr0y, rr0z, X.y, Y.y, Z.y);
        f16step(a0, rr0x, rr0y, rr0z, X.z, Y.z, Z.z);
        f16step(a0, rr0x, rr0y, rr0z, X.w, Y.w, Z.w);
        f16step(a1, rr1x, rr1y, rr1z, X.x, Y.x, Z.x);
        f16step(a1, rr1x, rr1y, rr1z, X.y, Y.y, Z.y);
        f16step(a1, rr1x, rr1y, rr1z, X.z, Y.z, Z.z);
        f16step(a1, rr1x, rr1y, rr1z, X.w, Y.w, Z.w);
        f16step(a2, rr2x, rr2y, rr2z, X.x, Y.x, Z.x);
        f16step(a2, rr2x, rr2y, rr2z, X.y, Y.y, Z.y);
        f16step(a2, rr2x, rr2y, rr2z, X.z, Y.z, Z.z);
        f16step(a2, rr2x, rr2y, rr2z, X.w, Y.w, Z.w);
        f16step(a3, rr3x, rr3y, rr3z, X.x, Y.x, Z.x);
        f16step(a3, rr3x, rr3y, rr3z, X.y, Y.y, Z.y);
        f16step(a3, rr3x, rr3y, rr3z, X.z, Y.z, Z.z);
        f16step(a3, rr3x, rr3y, rr3z, X.w, Y.w, Z.w);
    }

    const float rm0 = fminf(lo16f(a0), hi16f(a0));
    const float rm1 = fminf(lo16f(a1), hi16f(a1));
    const float rm2 = fminf(lo16f(a2), hi16f(a2));
    const float rm3 = fminf(lo16f(a3), hi16f(a3));

    float bm = fminf(fminf(rm0, rm1), fminf(rm2, rm3));
    #pragma unroll
    for (int off = 8; off; off >>= 1) bm = fminf(bm, __shfl_xor(bm, off, 64));

    // Max |coord| over both clusters (group reduce) for the f16 error bound.
    float Ml = fmaxf(fmaxf(fmaxf(fabsf(r0x), fabsf(r0y)), fmaxf(fabsf(r0z), fabsf(r1x))),
               fmaxf(fmaxf(fabsf(r1y), fabsf(r1z)), fmaxf(fabsf(r2x), fabsf(r2y))));
    Ml = fmaxf(Ml, fmaxf(fmaxf(fabsf(r2z), fabsf(r3x)), fmaxf(fabsf(r3y), fabsf(r3z))));
    Ml = fmaxf(Ml, fmaxf(fmaxf(fabsf(c0x), fabsf(c0y)), fmaxf(fabsf(c0z), fabsf(c1x))));
    Ml = fmaxf(Ml, fmaxf(fmaxf(fabsf(c1y), fabsf(c1z)), fmaxf(fabsf(c2x), fabsf(c2y))));
    Ml = fmaxf(Ml, fmaxf(fmaxf(fabsf(c2z), fabsf(c3x)), fmaxf(fabsf(c3y), fabsf(c3z))));
    #pragma unroll
    for (int off = 8; off; off >>= 1) Ml = fmaxf(Ml, __shfl_xor(Ml, off, 64));

    // Rigorous bound (u=2^-11): |d2_h-d2| <= 2*sqrt(3)*u*sqrt(d2)*(2M+sqrt(d2))
    // + 3u*d2 + denorm slack  ==>  0.0034*M*sqrt(d2) dominant. Use ~2x margin.
    const float eps = 0.006f * (Ml * sqrtf(bm) + bm) + 1e-3f;
    const float T = bm + 2.0f * eps;

    // Candidate rows (row = 4t + s; ascending = (t,s) lex).
    int fb = (rm0 <= T ? 1 : 0) | (rm1 <= T ? 2 : 0) |
             (rm2 <= T ? 4 : 0) | (rm3 <= T ? 8 : 0);

    float bestVal = FLT_MAX;
    int bestRow = 0, bestCol = 0;
    while (true) {
        int rl = fb ? (4 * t + __builtin_ctz((unsigned)fb)) : 999;
        int rstar = rl;
        #pragma unroll
        for (int off = 8; off; off >>= 1) {
            const int o = __shfl_xor(rstar, off, 64);
            rstar = o < rstar ? o : rstar;
        }
        if (!__ballot(rstar != 999)) break;   // all groups done
        if (rstar != 999) {
            if (rl == rstar) fb &= fb - 1;    // unique owner clears its bit
            const int ss = rstar & 3, tt = rstar >> 2;
            const float vx = __shfl(sel4(ss, r0x, r1x, r2x, r3x), gsh + tt, 64);
            const float vy = __shfl(sel4(ss, r0y, r1y, r2y, r3y), gsh + tt, 64);
            const float vz = __shfl(sel4(ss, r0z, r1z, r2z, r3z), gsh + tt, 64);
            const float e0 = d2np(vx, vy, vz, c0x, c0y, c0z);
            const float e1 = d2np(vx, vy, vz, c1x, c1y, c1z);
            const float e2 = d2np(vx, vy, vz, c2x, c2y, c2z);
            const float e3 = d2np(vx, vy, vz, c3x, c3y, c3z);
            float rmn = fminf(fminf(e0, e1), fminf(e2, e3));
            #pragma unroll
            for (int off = 8; off; off >>= 1) rmn = fminf(rmn, __shfl_xor(rmn, off, 64));
            if (rmn < bestVal) {   // strict <: earlier (ascending) row wins ties
                bestVal = rmn;
                bestRow = rstar;
                const unsigned h0 = (unsigned)(__ballot(e0 == rmn) >> gsh) & 0xFFFFu;
                const unsigned h1 = (unsigned)(__ballot(e1 == rmn) >> gsh) & 0xFFFFu;
                const unsigned h2 = (unsigned)(__ballot(e2 == rmn) >> gsh) & 0xFFFFu;
                const unsigned h3 = (unsigned)(__ballot(e3 == rmn) >> gsh) & 0xFFFFu;
                const int t2i = __builtin_ctz(h0 | h1 | h2 | h3);
                const int s2 = (h0 >> t2i) & 1 ? 0 : (h1 >> t2i) & 1 ? 1
                             : (h2 >> t2i) & 1 ? 2 : 3;
                bestCol = 4 * t2i + s2;       // first col attaining the row min
            }
        }
    }

    const int s1 = bestRow & 3, t1 = bestRow >> 2;
    const float v1x = __shfl(sel4(s1, r0x, r1x, r2x, r3x), gsh + t1, 64);
    const float v1y = __shfl(sel4(s1, r0y, r1y, r2y, r3y), gsh + t1, 64);
    const float v1z = __shfl(sel4(s1, r0z, r1z, r2z, r3z), gsh + t1, 64);
    const int s2c = bestCol & 3, t2c = bestCol >> 2;
    const float v2x = __shfl(sel4(s2c, c0x, c1x, c2x, c3x), gsh + t2c, 64);
    const float v2y = __shfl(sel4(s2c, c0y, c1y, c2y, c3y), gsh + t2c, 64);
    const float v2z = __shfl(sel4(s2c, c0z, c1z, c2z, c3z), gsh + t2c, 64);

    float dx = v1x - v2x, dy = v1y - v2y, dz = v1z - v2z;
    const float lend = sqrtf(dx * dx + dy * dy + dz * dz);
    if (lend > 0.f) {
        const float inv = 1.0f / lend;
        dx *= inv; dy *= inv; dz *= inv;
    }

    if (e < E) {
        float* orow = out + (size_t)e * 19;
        float o;
        if (t < 3)       o = sel3(t,     v1x, v1y, v1z);
        else if (t < 6)  o = sel3(t - 3, v2x, v2y, v2z);
        else if (t < 9)  o = sel3(t - 6, dx, dy, dz);
        else if (t == 9) o = lend;
        else {
            const int k = t - 10;
            o = sel3(k / 3, dx, dy, dz) * sel3(k % 3, dx, dy, dz);
        }
        orow[t] = o;
        if (t < 3) {
            const int k = t + 6;   // elements 16,17,18 = B[6..8]
            orow[16 + t] = sel3(k / 3, dx, dy, dz) * sel3(k % 3, dx, dy, dz);
        }
    }
}

extern "C" void kernel_launch(void* const* d_in, const int* in_sizes, int n_in,
                              void* d_out, int out_size, void* d_ws, size_t ws_size,
                              hipStream_t stream) {
    const float* data   = (const float*)d_in[0];
    const int*   clusts = (const int*)d_in[1];
    const int*   eidx   = (const int*)d_in[2];
    float*       out    = (float*)d_out;
    const int E = in_sizes[2] / 2;            // edge_index is (2, E)
    const int blocks = (E + 15) / 16;         // 16 edges per block (4 waves x 4)
    clustgeo_f16filter<<<blocks, 256, 0, stream>>>(data, clusts, eidx, out, E);
}